// Round 6
// baseline (577.930 us; speedup 1.0000x reference)
//
#include <hip/hip_runtime.h>

// FactorizedSpectralConv2d, round 5 (resubmit; prior run died to container infra).
// Kill the mix's serial load+select chains:
//  - Pre-kernel expands w (f32 [i][o][k][2]) into W2h: f16 MFMA A-fragments
//    [k 32][chunk 8][m 8][lane 64] -> uint2, in d_ws (1 MB/branch). The real
//    expansion W2 = [[re,-im],[im,re]] is baked in at the right lane position.
//  - Mix inner loop is now 16 coalesced 8B loads + 16 MFMA: no selects, no packs,
//    no dependent VALU; loads are independent and issue together.
//  - Prefetch at the r2b position (after Ys barrier): latency hides under mix.
//  - Epilogue: BR0 nontemporal stores, BR1 unsafeAtomicAdd.

typedef _Float16 half8  __attribute__((ext_vector_type(8)));
typedef _Float16 half4v __attribute__((ext_vector_type(4)));
typedef _Float16 half2v __attribute__((ext_vector_type(2)));
typedef float    floatx4 __attribute__((ext_vector_type(4)));

#define TWO_PI_OVER_128 0.049087385212340517f

__device__ __forceinline__ unsigned int packh2(float a, float b) {
    half2v h; h[0] = (_Float16)a; h[1] = (_Float16)b;
    return __builtin_bit_cast(unsigned int, h);
}
__device__ __forceinline__ half8  ash8(uint4 u) { return __builtin_bit_cast(half8, u); }
__device__ __forceinline__ half4v ash4(uint2 u) { return __builtin_bit_cast(half4v, u); }

#define MFMA_K16(A,B,C) __builtin_amdgcn_mfma_f32_16x16x16f16((A),(B),(C),0,0,0)

#define YS_PK 324   // halves per k slice (16*20 + 4 pad)
#define YS_PR 20    // halves per t row  (16 r + 4 pad)

// ---- pre-kernel: expand both branches' weights into A-fragment layout ----
// entry e (per branch) = ((k*8 + c)*8 + m)*64 + lane ; value = uint2 of 4 halves:
//   h = {i_loc = (lane>>4)*2 + hp, comp} ; o' = m*16 + (lane&15), oc = o'&1
//   oc==0 (re row): (re, -im) ; oc==1 (im row): (im, re)     [i = c*8 + i_loc]
__global__ __launch_bounds__(256) void w2expand(const float* __restrict__ w0,
                                                const float* __restrict__ w1,
                                                uint2* __restrict__ W2h)
{
    int g = blockIdx.x * 256 + threadIdx.x;       // 2 * 131072 entries
    const float* w = (g >> 17) ? w1 : w0;
    int e    = g & 131071;
    int lane = e & 63;
    int m    = (e >> 6) & 7;
    int c    = (e >> 9) & 7;
    int k    = e >> 12;
    int mrow = lane & 15, q = lane >> 4;
    int o  = (m * 16 + mrow) >> 1;
    int oc = mrow & 1;
    unsigned int h2[2];
#pragma unroll
    for (int hp = 0; hp < 2; ++hp) {
        int i = c * 8 + q * 2 + hp;
        const float* wp = w + ((i * 64 + o) * 32 + k) * 2;
        float re = wp[0], im = wp[1];
        float v0 = oc ? im : re;
        float v1 = oc ? re : -im;
        h2[hp] = packh2(v0, v1);
    }
    W2h[g] = make_uint2(h2[0], h2[1]);
}

// BR=0: width branch (DFT axis contiguous), writes out.
// BR=1: height branch (DFT axis strided by 128), accumulates into out.
template<int BR>
__global__ __launch_bounds__(1024, 4) void spectral(const float* __restrict__ x,
                                                    const uint2* __restrict__ w2,
                                                    float* __restrict__ out)
{
    __shared__ uint4 Ubuf[36864 / 16];            // Xs (34816 B), later Zs (36864 B)
    __shared__ unsigned short Ys[32 * YS_PK];     // 20736 B

    unsigned short* Xs = (unsigned short*)Ubuf;
    unsigned int*   Zs = (unsigned int*)Ubuf;

    const int tid  = threadIdx.x;
    const int wv   = tid >> 6;
    const int lane = tid & 63;
    const int mrow = tid & 15;
    const int quad = (tid >> 4) & 3;
    const int bx   = blockIdx.x;
    const int b    = bx >> 3;
    const int tile = bx & 7;

    const long xb = (long)b * 1048576 + (BR == 0 ? tile * 2048 : tile * 16);
    const long ob = xb;

    // ---- stage-1 A fragments: F[kp][d], kp-tile fixed per wave ----
    const int kptile = wv & 3;
    half8 Ff[4];
#pragma unroll
    for (int s = 0; s < 4; ++s)
#pragma unroll
        for (int j = 0; j < 8; ++j) {
            int d  = s * 32 + quad * 8 + j;
            int kp = kptile * 16 + mrow;
            int k  = kp >> 1;
            float ang = TWO_PI_OVER_128 * (float)((k * d) & 127);
            float v = (kp & 1) ? -sinf(ang) : cosf(ang);
            Ff[s][j] = (_Float16)v;
        }

    // ---- mix accumulators: wave wv owns k = {2wv, 2wv+1}; Z2[o' 0..127][t 0..15] ----
    floatx4 acc[2][8];
#pragma unroll
    for (int kk = 0; kk < 2; ++kk)
#pragma unroll
        for (int m = 0; m < 8; ++m)
            acc[kk][m] = (floatx4){0.f, 0.f, 0.f, 0.f};

    // ---- prologue: stage chunk 0 into Xs ----
    if (BR == 0) {
#pragma unroll
        for (int p = 0; p < 4; ++p) {
            int idx = p * 1024 + tid;
            int col = idx >> 5, dg = idx & 31;
            int i = col >> 4, t = col & 15;
            const float4 v = *(const float4*)(x + xb + (long)i * 16384 + t * 128 + dg * 4);
            *(uint2*)&Xs[col * 136 + dg * 4] = make_uint2(packh2(v.x, v.y), packh2(v.z, v.w));
        }
    } else {
#pragma unroll
        for (int p = 0; p < 4; ++p) {
            int i  = (tid >> 9) + p * 2;
            int d  = (tid >> 2) & 127;
            int tq = (tid & 3) * 4;
            const float4 v = *(const float4*)(x + xb + (long)i * 16384 + d * 128 + tq);
            int colb = i * 16 + tq;
            Xs[(colb + 0) * 136 + d] = __builtin_bit_cast(unsigned short, (_Float16)v.x);
            Xs[(colb + 1) * 136 + d] = __builtin_bit_cast(unsigned short, (_Float16)v.y);
            Xs[(colb + 2) * 136 + d] = __builtin_bit_cast(unsigned short, (_Float16)v.z);
            Xs[(colb + 3) * 136 + d] = __builtin_bit_cast(unsigned short, (_Float16)v.w);
        }
    }
    __syncthreads();

    // ================= chunk loop: 8 chunks x 8 input channels =================
    for (int c = 0; c < 8; ++c) {
        // ---------- stage 1: Y = F x X -> Ys[k][t][r=2i+c] ----------
#pragma unroll
        for (int cc = 0; cc < 2; ++cc) {
            int i = (wv >> 2) * 2 + cc;
            floatx4 y4 = {0.f, 0.f, 0.f, 0.f};
#pragma unroll
            for (int s = 0; s < 4; ++s) {
                uint4 bv = *(const uint4*)&Xs[(i * 16 + mrow) * 136 + s * 32 + quad * 8];
                y4 = __builtin_amdgcn_mfma_f32_16x16x32_f16(Ff[s], ash8(bv), y4, 0, 0, 0);
            }
            // C layout: t = mrow, kp = kptile*16 + quad*4 + r  -> k0 = kp>>1, (re,im) pairs
            int k0 = kptile * 8 + quad * 2;
            unsigned int* yw = (unsigned int*)Ys;
            yw[(k0    ) * (YS_PK / 2) + mrow * (YS_PR / 2) + i] = packh2(y4[0], y4[1]);
            yw[(k0 + 1) * (YS_PK / 2) + mrow * (YS_PR / 2) + i] = packh2(y4[2], y4[3]);
        }
        __syncthreads();   // Ys ready; Xs reads done

        // ---------- prefetch next chunk's x (latency hides under mix) ----------
        float4 pf[4];
        if (c < 7) {
            if (BR == 0) {
#pragma unroll
                for (int p = 0; p < 4; ++p) {
                    int idx = p * 1024 + tid;
                    int col = idx >> 5, dg = idx & 31;
                    int i = col >> 4, t = col & 15;
                    pf[p] = *(const float4*)(x + xb + (long)((c + 1) * 8 + i) * 16384 + t * 128 + dg * 4);
                }
            } else {
#pragma unroll
                for (int p = 0; p < 4; ++p) {
                    int i  = (tid >> 9) + p * 2;
                    int d  = (tid >> 2) & 127;
                    int tq = (tid & 3) * 4;
                    pf[p] = *(const float4*)(x + xb + (long)((c + 1) * 8 + i) * 16384 + d * 128 + tq);
                }
            }
        }

        // ---------- mix (MFMA): per k, Z2 += W2 x Y2 — pure loads + MFMA ----------
        {
            half4v bf0 = ash4(*(const uint2*)&Ys[(wv * 2    ) * YS_PK + mrow * YS_PR + quad * 4]);
            half4v bf1 = ash4(*(const uint2*)&Ys[(wv * 2 + 1) * YS_PK + mrow * YS_PR + quad * 4]);
            // A-frag table: entry((k,c,m)) = ((k*8 + c)*8 + m)*64 + lane
            const uint2* wp = w2 + (((2 * wv) * 8 + c) * 8) * 64 + lane;
#pragma unroll
            for (int m = 0; m < 8; ++m) {
                uint2 a0u = wp[m * 64];
                uint2 a1u = wp[m * 64 + 4096];   // k+1 is 8*8*64 entries away
                acc[0][m] = MFMA_K16(ash4(a0u), bf0, acc[0][m]);
                acc[1][m] = MFMA_K16(ash4(a1u), bf1, acc[1][m]);
            }
        }

        // ---------- write prefetched chunk into Xs ----------
        if (c < 7) {
            if (BR == 0) {
#pragma unroll
                for (int p = 0; p < 4; ++p) {
                    int idx = p * 1024 + tid;
                    int col = idx >> 5, dg = idx & 31;
                    *(uint2*)&Xs[col * 136 + dg * 4] =
                        make_uint2(packh2(pf[p].x, pf[p].y), packh2(pf[p].z, pf[p].w));
                }
            } else {
#pragma unroll
                for (int p = 0; p < 4; ++p) {
                    int d  = (tid >> 2) & 127;
                    int tq = (tid & 3) * 4;
                    int colb = ((tid >> 9) + p * 2) * 16 + tq;
                    Xs[(colb + 0) * 136 + d] = __builtin_bit_cast(unsigned short, (_Float16)pf[p].x);
                    Xs[(colb + 1) * 136 + d] = __builtin_bit_cast(unsigned short, (_Float16)pf[p].y);
                    Xs[(colb + 2) * 136 + d] = __builtin_bit_cast(unsigned short, (_Float16)pf[p].z);
                    Xs[(colb + 3) * 136 + d] = __builtin_bit_cast(unsigned short, (_Float16)pf[p].w);
                }
            }
        }
        __syncthreads();   // Xs(c+1) ready; Ys(c) reads done
    }

    // ================= stage 3: out = G x Z, quarter of o at a time =================
    const int dt  = wv & 7;
    const int ctb = (wv >> 3) * 8;
    const int dp  = dt * 16 + mrow;
    half8 Gf[2];
#pragma unroll
    for (int s = 0; s < 2; ++s)
#pragma unroll
        for (int j = 0; j < 8; ++j) {
            int kp = s * 32 + quad * 8 + j;
            int k  = kp >> 1;
            float ang = TWO_PI_OVER_128 * (float)((k * dp) & 127);
            float v;
            if (kp == 0)      v = 1.f / 128.f;
            else if (kp == 1) v = 0.f;                       // irfft drops DC imag
            else v = (kp & 1) ? -(2.f / 128.f) * sinf(ang) : (2.f / 128.f) * cosf(ang);
            Gf[s][j] = (_Float16)v;
        }

    for (int q = 0; q < 4; ++q) {
        __syncthreads();   // prev quarter's Zs reads (or chunk-7 traffic) done
        // slot = k ^ 8*quad; reader XORs the same value, so it cancels
#pragma unroll
        for (int mm = 0; mm < 2; ++mm) {
            const int m = q * 2 + mm;
#pragma unroll
            for (int kk = 0; kk < 2; ++kk) {
                const int slot = (wv * 2 + kk) ^ (quad * 8);
                const int col  = (mm * 8 + quad * 2) * 16 + mrow;
                Zs[ col       * 36 + slot] = packh2(acc[kk][m][0], acc[kk][m][1]);
                Zs[(col + 16) * 36 + slot] = packh2(acc[kk][m][2], acc[kk][m][3]);
            }
        }
        __syncthreads();   // Zs ready

#pragma unroll
        for (int cc = 0; cc < 8; ++cc) {
            const int ct  = ctb + cc;
            const int col = ct * 16 + mrow;
            const int swz = (ct & 6) << 2;
            floatx4 o4 = {0.f, 0.f, 0.f, 0.f};
#pragma unroll
            for (int s = 0; s < 2; ++s) {
                uint4 zv = *(const uint4*)&Zs[col * 36 + ((s * 16 + quad * 4) ^ swz)];
                o4 = __builtin_amdgcn_mfma_f32_16x16x32_f16(Gf[s], ash8(zv), o4, 0, 0, 0);
            }
            const int oo = q * 16 + ct;
            const int t  = mrow;
            const int db = dt * 16 + quad * 4;
            if (BR == 0) {
                // nontemporal: no L2 write-allocate -> no phantom out-line fetch
                __builtin_nontemporal_store(o4, (floatx4*)(out + ob + (long)oo * 16384 + t * 128 + db));
            } else {
                // fire-and-forget HW f32 atomics: no dependent load chain
                float* p = out + ob + (long)oo * 16384 + (long)db * 128 + t;
                unsafeAtomicAdd(p,       o4[0]);
                unsafeAtomicAdd(p + 128, o4[1]);
                unsafeAtomicAdd(p + 256, o4[2]);
                unsafeAtomicAdd(p + 384, o4[3]);
            }
        }
    }
}

extern "C" void kernel_launch(void* const* d_in, const int* in_sizes, int n_in,
                              void* d_out, int out_size, void* d_ws, size_t ws_size,
                              hipStream_t stream) {
    const float* x  = (const float*)d_in[0];
    const float* w0 = (const float*)d_in[1];
    const float* w1 = (const float*)d_in[2];
    float* out = (float*)d_out;

    uint2* W2h = (uint2*)d_ws;                 // 2 x 131072 uint2 = 2 MB

    // expand both branches' weights into A-fragment tables (ordered on stream)
    w2expand<<<dim3(1024), dim3(256), 0, stream>>>(w0, w1, W2h);

    dim3 grid(256);    // 32 batches x 8 line-tiles
    dim3 block(1024);

    spectral<0><<<grid, block, 0, stream>>>(x, W2h,          out);  // width: writes out
    spectral<1><<<grid, block, 0, stream>>>(x, W2h + 131072, out);  // height: accumulates
}

// Round 7
// 574.504 us; speedup vs baseline: 1.0060x; 1.0060x over previous
//
#include <hip/hip_runtime.h>

// FactorizedSpectralConv2d, round 7: break the single-workgroup lockstep.
// Block = 512 threads (8 waves) owning (batch, 16-line tile, o-HALF); grid 512 ->
// TWO independent blocks per CU (LDS 55.5KB x2 = 111KB, regs <=128 via
// __launch_bounds__(512,4)). When one block drains vmcnt/barriers, the other runs.
// Stage 1 (DFT) duplicated between o-half twins (cheap); mix + stage3 halve.
// Mix acc = 2 k-pairs x 2 modes x 4 m-tiles = 64 AGPR/wave (o' in [oh*64, oh*64+64)).
// Staging split: group A (i 0..3) issued at chunk top, written after B1; group B
// (i 4..7) issued after A's write, written after mix -> pf liveness 16 VGPRs.
// W2h pre-expansion, nontemporal BR0 stores, BR1 unsafeAtomicAdd kept from r5/r6.

typedef _Float16 half8  __attribute__((ext_vector_type(8)));
typedef _Float16 half4v __attribute__((ext_vector_type(4)));
typedef _Float16 half2v __attribute__((ext_vector_type(2)));
typedef float    floatx4 __attribute__((ext_vector_type(4)));

#define TWO_PI_OVER_128 0.049087385212340517f

__device__ __forceinline__ unsigned int packh2(float a, float b) {
    half2v h; h[0] = (_Float16)a; h[1] = (_Float16)b;
    return __builtin_bit_cast(unsigned int, h);
}
__device__ __forceinline__ half8  ash8(uint4 u) { return __builtin_bit_cast(half8, u); }
__device__ __forceinline__ half4v ash4(uint2 u) { return __builtin_bit_cast(half4v, u); }

#define MFMA_K16(A,B,C) __builtin_amdgcn_mfma_f32_16x16x16f16((A),(B),(C),0,0,0)

#define YS_PK 324   // halves per k slice (16*20 + 4 pad)
#define YS_PR 20    // halves per t row  (16 r + 4 pad)

// ---- pre-kernel: expand both branches' weights into A-fragment layout ----
// entry e (per branch) = ((k*8 + c)*8 + m)*64 + lane ; value = uint2 of 4 halves:
//   h = {i_loc = (lane>>4)*2 + hp, comp} ; o' = m*16 + (lane&15), oc = o'&1
//   oc==0 (re row): (re, -im) ; oc==1 (im row): (im, re)     [i = c*8 + i_loc]
__global__ __launch_bounds__(256) void w2expand(const float* __restrict__ w0,
                                                const float* __restrict__ w1,
                                                uint2* __restrict__ W2h)
{
    int g = blockIdx.x * 256 + threadIdx.x;       // 2 * 131072 entries
    const float* w = (g >> 17) ? w1 : w0;
    int e    = g & 131071;
    int lane = e & 63;
    int m    = (e >> 6) & 7;
    int c    = (e >> 9) & 7;
    int k    = e >> 12;
    int mrow = lane & 15, q = lane >> 4;
    int o  = (m * 16 + mrow) >> 1;
    int oc = mrow & 1;
    unsigned int h2[2];
#pragma unroll
    for (int hp = 0; hp < 2; ++hp) {
        int i = c * 8 + q * 2 + hp;
        const float* wp = w + ((i * 64 + o) * 32 + k) * 2;
        float re = wp[0], im = wp[1];
        float v0 = oc ? im : re;
        float v1 = oc ? re : -im;
        h2[hp] = packh2(v0, v1);
    }
    W2h[g] = make_uint2(h2[0], h2[1]);
}

// BR=0: width branch (DFT axis contiguous), writes out.
// BR=1: height branch (DFT axis strided by 128), accumulates into out.
template<int BR>
__global__ __launch_bounds__(512, 4) void spectral(const float* __restrict__ x,
                                                   const uint2* __restrict__ w2,
                                                   float* __restrict__ out)
{
    __shared__ uint4 Ubuf[34816 / 16];            // Xs (34816 B) / Zs (18432 B)
    __shared__ unsigned short Ys[32 * YS_PK];     // 20736 B   -> total 55552 B

    unsigned short* Xs = (unsigned short*)Ubuf;
    unsigned int*   Zs = (unsigned int*)Ubuf;

    const int tid  = threadIdx.x;
    const int wv   = tid >> 6;        // 0..7
    const int lane = tid & 63;
    const int mrow = tid & 15;
    const int quad = (tid >> 4) & 3;
    const int bx   = blockIdx.x;
    const int oh   = bx & 1;          // o-half
    const int tile = (bx >> 1) & 7;
    const int b    = bx >> 4;

    const long xb = (long)b * 1048576 + (BR == 0 ? tile * 2048 : tile * 16);
    const long ob = xb;

    // ---- stage-1 A fragments: F[kp][d], kp-tile fixed per wave ----
    const int kptile = wv & 3;
    half8 Ff[4];
#pragma unroll
    for (int s = 0; s < 4; ++s)
#pragma unroll
        for (int j = 0; j < 8; ++j) {
            int d  = s * 32 + quad * 8 + j;
            int kp = kptile * 16 + mrow;
            int k  = kp >> 1;
            float ang = TWO_PI_OVER_128 * (float)((k * d) & 127);
            float v = (kp & 1) ? -sinf(ang) : cosf(ang);
            Ff[s][j] = (_Float16)v;
        }

    // ---- mix accumulators: wave owns k-pairs {wv, wv+8}, o' in [oh*64, oh*64+64) ----
    // acc[kpsel][kk][m]: o' = (oh*4+m)*16 + quad*4 + r, t = mrow
    floatx4 acc[2][2][4];
#pragma unroll
    for (int a = 0; a < 2; ++a)
#pragma unroll
        for (int kk = 0; kk < 2; ++kk)
#pragma unroll
            for (int m = 0; m < 4; ++m)
                acc[a][kk][m] = (floatx4){0.f, 0.f, 0.f, 0.f};

    // ---- staging helpers (512 threads, 8 x float4 per chunk, split A/B) ----
    // BR0: idx = p*512+tid -> col=idx>>5 (i=col>>4, t=col&15), dg=idx&31
    // BR1: i = p, d = (tid>>2)&127, tq = (tid&3)*4

    // ---- prologue: stage chunk 0 into Xs (two groups of 4) ----
#pragma unroll
    for (int g = 0; g < 2; ++g) {
        float4 v[4];
#pragma unroll
        for (int pp = 0; pp < 4; ++pp) {
            int p = g * 4 + pp;
            if (BR == 0) {
                int idx = p * 512 + tid;
                int col = idx >> 5, dg = idx & 31;
                v[pp] = *(const float4*)(x + xb + (long)(col >> 4) * 16384 + (col & 15) * 128 + dg * 4);
            } else {
                int d = (tid >> 2) & 127, tq = (tid & 3) * 4;
                v[pp] = *(const float4*)(x + xb + (long)p * 16384 + d * 128 + tq);
            }
        }
#pragma unroll
        for (int pp = 0; pp < 4; ++pp) {
            int p = g * 4 + pp;
            if (BR == 0) {
                int idx = p * 512 + tid;
                int col = idx >> 5, dg = idx & 31;
                *(uint2*)&Xs[col * 136 + dg * 4] =
                    make_uint2(packh2(v[pp].x, v[pp].y), packh2(v[pp].z, v[pp].w));
            } else {
                int d = (tid >> 2) & 127, tq = (tid & 3) * 4;
                int colb = p * 16 + tq;
                Xs[(colb + 0) * 136 + d] = __builtin_bit_cast(unsigned short, (_Float16)v[pp].x);
                Xs[(colb + 1) * 136 + d] = __builtin_bit_cast(unsigned short, (_Float16)v[pp].y);
                Xs[(colb + 2) * 136 + d] = __builtin_bit_cast(unsigned short, (_Float16)v[pp].z);
                Xs[(colb + 3) * 136 + d] = __builtin_bit_cast(unsigned short, (_Float16)v[pp].w);
            }
        }
    }
    __syncthreads();

    // ================= chunk loop: 8 chunks x 8 input channels =================
    for (int c = 0; c < 8; ++c) {
        // ---------- issue group A (i 0..3) of next chunk: in flight across stage1+B1 ----------
        float4 pfA[4];
        if (c < 7) {
#pragma unroll
            for (int p = 0; p < 4; ++p) {
                if (BR == 0) {
                    int idx = p * 512 + tid;
                    int col = idx >> 5, dg = idx & 31;
                    pfA[p] = *(const float4*)(x + xb + (long)((c + 1) * 8 + (col >> 4)) * 16384 + (col & 15) * 128 + dg * 4);
                } else {
                    int d = (tid >> 2) & 127, tq = (tid & 3) * 4;
                    pfA[p] = *(const float4*)(x + xb + (long)((c + 1) * 8 + p) * 16384 + d * 128 + tq);
                }
            }
        }

        // ---------- stage 1: Y = F x X -> Ys[k][t][r=2i+c]  (wave does 4 i) ----------
#pragma unroll
        for (int cc = 0; cc < 4; ++cc) {
            int i = (wv >> 2) * 4 + cc;
            floatx4 y4 = {0.f, 0.f, 0.f, 0.f};
#pragma unroll
            for (int s = 0; s < 4; ++s) {
                uint4 bv = *(const uint4*)&Xs[(i * 16 + mrow) * 136 + s * 32 + quad * 8];
                y4 = __builtin_amdgcn_mfma_f32_16x16x32_f16(Ff[s], ash8(bv), y4, 0, 0, 0);
            }
            int k0 = kptile * 8 + quad * 2;
            unsigned int* yw = (unsigned int*)Ys;
            yw[(k0    ) * (YS_PK / 2) + mrow * (YS_PR / 2) + i] = packh2(y4[0], y4[1]);
            yw[(k0 + 1) * (YS_PK / 2) + mrow * (YS_PR / 2) + i] = packh2(y4[2], y4[3]);
        }
        __syncthreads();   // B1: Ys ready; Xs reads done

        // ---------- write group A into Xs; issue group B (i 4..7) ----------
        float4 pfB[4];
        if (c < 7) {
#pragma unroll
            for (int p = 0; p < 4; ++p) {
                if (BR == 0) {
                    int idx = p * 512 + tid;
                    int col = idx >> 5, dg = idx & 31;
                    *(uint2*)&Xs[col * 136 + dg * 4] =
                        make_uint2(packh2(pfA[p].x, pfA[p].y), packh2(pfA[p].z, pfA[p].w));
                } else {
                    int d = (tid >> 2) & 127, tq = (tid & 3) * 4;
                    int colb = p * 16 + tq;
                    Xs[(colb + 0) * 136 + d] = __builtin_bit_cast(unsigned short, (_Float16)pfA[p].x);
                    Xs[(colb + 1) * 136 + d] = __builtin_bit_cast(unsigned short, (_Float16)pfA[p].y);
                    Xs[(colb + 2) * 136 + d] = __builtin_bit_cast(unsigned short, (_Float16)pfA[p].z);
                    Xs[(colb + 3) * 136 + d] = __builtin_bit_cast(unsigned short, (_Float16)pfA[p].w);
                }
            }
#pragma unroll
            for (int p = 0; p < 4; ++p) {
                if (BR == 0) {
                    int idx = (p + 4) * 512 + tid;
                    int col = idx >> 5, dg = idx & 31;
                    pfB[p] = *(const float4*)(x + xb + (long)((c + 1) * 8 + (col >> 4)) * 16384 + (col & 15) * 128 + dg * 4);
                } else {
                    int d = (tid >> 2) & 127, tq = (tid & 3) * 4;
                    pfB[p] = *(const float4*)(x + xb + (long)((c + 1) * 8 + 4 + p) * 16384 + d * 128 + tq);
                }
            }
        }

        // ---------- mix (MFMA): 4 modes per wave (k-pairs wv, wv+8), o-half oh ----------
        {
            half4v bfA0 = ash4(*(const uint2*)&Ys[(2 * wv     ) * YS_PK + mrow * YS_PR + quad * 4]);
            half4v bfA1 = ash4(*(const uint2*)&Ys[(2 * wv + 1 ) * YS_PK + mrow * YS_PR + quad * 4]);
            half4v bfB0 = ash4(*(const uint2*)&Ys[(2 * wv + 16) * YS_PK + mrow * YS_PR + quad * 4]);
            half4v bfB1 = ash4(*(const uint2*)&Ys[(2 * wv + 17) * YS_PK + mrow * YS_PR + quad * 4]);
            // A-frag table: entry((k,c,m)) = ((k*8 + c)*8 + m)*64 + lane
            const uint2* wpA = w2 + (((2 * wv) * 8 + c) * 8 + oh * 4) * 64 + lane;
            const uint2* wpB = wpA + 65536;   // k += 16
#pragma unroll
            for (int m = 0; m < 4; ++m) {
                acc[0][0][m] = MFMA_K16(ash4(wpA[m * 64       ]), bfA0, acc[0][0][m]);
                acc[0][1][m] = MFMA_K16(ash4(wpA[m * 64 + 4096]), bfA1, acc[0][1][m]);
                acc[1][0][m] = MFMA_K16(ash4(wpB[m * 64       ]), bfB0, acc[1][0][m]);
                acc[1][1][m] = MFMA_K16(ash4(wpB[m * 64 + 4096]), bfB1, acc[1][1][m]);
            }
        }

        // ---------- write group B into Xs ----------
        if (c < 7) {
#pragma unroll
            for (int p = 0; p < 4; ++p) {
                if (BR == 0) {
                    int idx = (p + 4) * 512 + tid;
                    int col = idx >> 5, dg = idx & 31;
                    *(uint2*)&Xs[col * 136 + dg * 4] =
                        make_uint2(packh2(pfB[p].x, pfB[p].y), packh2(pfB[p].z, pfB[p].w));
                } else {
                    int d = (tid >> 2) & 127, tq = (tid & 3) * 4;
                    int colb = (4 + p) * 16 + tq;
                    Xs[(colb + 0) * 136 + d] = __builtin_bit_cast(unsigned short, (_Float16)pfB[p].x);
                    Xs[(colb + 1) * 136 + d] = __builtin_bit_cast(unsigned short, (_Float16)pfB[p].y);
                    Xs[(colb + 2) * 136 + d] = __builtin_bit_cast(unsigned short, (_Float16)pfB[p].z);
                    Xs[(colb + 3) * 136 + d] = __builtin_bit_cast(unsigned short, (_Float16)pfB[p].w);
                }
            }
        }
        __syncthreads();   // B2: Xs(c+1) ready; Ys(c) reads done
    }

    // ================= stage 3: out = G x Z, one m-tile (8 o) per quarter =================
    const int dt = wv;                // d-block 0..7
    const int dp = dt * 16 + mrow;
    half8 Gf[2];
#pragma unroll
    for (int s = 0; s < 2; ++s)
#pragma unroll
        for (int j = 0; j < 8; ++j) {
            int kp = s * 32 + quad * 8 + j;
            int k  = kp >> 1;
            float ang = TWO_PI_OVER_128 * (float)((k * dp) & 127);
            float v;
            if (kp == 0)      v = 1.f / 128.f;
            else if (kp == 1) v = 0.f;                       // irfft drops DC imag
            else v = (kp & 1) ? -(2.f / 128.f) * sinf(ang) : (2.f / 128.f) * cosf(ang);
            Gf[s][j] = (_Float16)v;
        }

#pragma unroll
    for (int q = 0; q < 4; ++q) {
        __syncthreads();   // prev quarter's Zs reads (or chunk-7 Xs reads) done
        // write quarter q = m-tile q: o = oh*32 + q*8 + (quad*2 + (r>>1))
        // slot = kmode ^ 8*quad; reader XORs the same value, so it cancels
#pragma unroll
        for (int a = 0; a < 2; ++a)
#pragma unroll
            for (int kk = 0; kk < 2; ++kk) {
                const int kmode = 2 * (wv + a * 8) + kk;
                const int slot  = kmode ^ (quad * 8);
                const int col   = (quad * 2) * 16 + mrow;
                Zs[ col       * 36 + slot] = packh2(acc[a][kk][q][0], acc[a][kk][q][1]);
                Zs[(col + 16) * 36 + slot] = packh2(acc[a][kk][q][2], acc[a][kk][q][3]);
            }
        __syncthreads();   // Zs ready

#pragma unroll
        for (int cc = 0; cc < 8; ++cc) {
            const int ct  = cc;                  // o within quarter
            const int col = ct * 16 + mrow;
            const int swz = (ct & 6) << 2;
            floatx4 o4 = {0.f, 0.f, 0.f, 0.f};
#pragma unroll
            for (int s = 0; s < 2; ++s) {
                uint4 zv = *(const uint4*)&Zs[col * 36 + ((s * 16 + quad * 4) ^ swz)];
                o4 = __builtin_amdgcn_mfma_f32_16x16x32_f16(Gf[s], ash8(zv), o4, 0, 0, 0);
            }
            const int oo = oh * 32 + q * 8 + ct;
            const int t  = mrow;
            const int db = dt * 16 + quad * 4;
            if (BR == 0) {
                __builtin_nontemporal_store(o4, (floatx4*)(out + ob + (long)oo * 16384 + t * 128 + db));
            } else {
                float* p = out + ob + (long)oo * 16384 + (long)db * 128 + t;
                unsafeAtomicAdd(p,       o4[0]);
                unsafeAtomicAdd(p + 128, o4[1]);
                unsafeAtomicAdd(p + 256, o4[2]);
                unsafeAtomicAdd(p + 384, o4[3]);
            }
        }
    }
}

extern "C" void kernel_launch(void* const* d_in, const int* in_sizes, int n_in,
                              void* d_out, int out_size, void* d_ws, size_t ws_size,
                              hipStream_t stream) {
    const float* x  = (const float*)d_in[0];
    const float* w0 = (const float*)d_in[1];
    const float* w1 = (const float*)d_in[2];
    float* out = (float*)d_out;

    uint2* W2h = (uint2*)d_ws;                 // 2 x 131072 uint2 = 2 MB

    w2expand<<<dim3(1024), dim3(256), 0, stream>>>(w0, w1, W2h);

    dim3 grid(512);    // 32 batches x 8 line-tiles x 2 o-halves
    dim3 block(512);

    spectral<0><<<grid, block, 0, stream>>>(x, W2h,          out);  // width: writes out
    spectral<1><<<grid, block, 0, stream>>>(x, W2h + 131072, out);  // height: accumulates
}

// Round 8
// 503.223 us; speedup vs baseline: 1.1485x; 1.1416x over previous
//
#include <hip/hip_runtime.h>

// FactorizedSpectralConv2d, round 8: HALVE THE PHASE COUNT (controlled experiment).
// Back to 1024-thr / grid 256 (1 block/CU, no twin x re-read). Chunk = 16 input
// channels, 4 chunk iterations -> main-loop barrier phases 16 -> 8.
// Mix: one 16x16x32 f16 MFMA per (k, m-tile) spanning all 16 chunk channels
// (r = 2*i+comp in [0,32)); W2h table holds half8 A-fragments.
// Ys: [k][t][r], PR=40 halves, PK=648 halves (bank-spread, 16B-aligned b128 reads).
// Kept: W2h pre-expansion, reg-staged A/B split prefetch, BR0 nontemporal stores,
// BR1 unsafeAtomicAdd.

typedef _Float16 half8  __attribute__((ext_vector_type(8)));
typedef _Float16 half2v __attribute__((ext_vector_type(2)));
typedef float    floatx4 __attribute__((ext_vector_type(4)));

#define TWO_PI_OVER_128 0.049087385212340517f

__device__ __forceinline__ unsigned int packh2(float a, float b) {
    half2v h; h[0] = (_Float16)a; h[1] = (_Float16)b;
    return __builtin_bit_cast(unsigned int, h);
}
__device__ __forceinline__ half8 ash8(uint4 u) { return __builtin_bit_cast(half8, u); }

#define MFMA_K32(A,B,C) __builtin_amdgcn_mfma_f32_16x16x32_f16((A),(B),(C),0,0,0)

#define YS_PR 40    // halves per t row (32 r + 8 pad)  -> 80 B, 16B-aligned
#define YS_PK 648   // halves per k slice (16*40 + 8)   -> 1296 B, 16B-aligned, bank-spread

// ---- pre-kernel: expand weights into half8 A-fragments for the K=32 mix ----
// entry (per branch) = ((k*4 + c4)*8 + m)*64 + lane ; uint4 = 8 halves j=0..7:
//   k-slot r = quad*8 + j ; i = c4*16 + (r>>1) ; comp = r&1
//   o' = m*16 + mrow ; o = o'>>1 ; oc = o'&1
//   oc==0 (re row): comp0 -> re, comp1 -> -im ; oc==1 (im row): comp0 -> im, comp1 -> re
__global__ __launch_bounds__(256) void w2expand(const float* __restrict__ w0,
                                                const float* __restrict__ w1,
                                                uint4* __restrict__ W2h)
{
    int g = blockIdx.x * 256 + threadIdx.x;       // 2 * 65536 entries
    const float* w = (g >> 16) ? w1 : w0;
    int e    = g & 65535;
    int lane = e & 63;
    int m    = (e >> 6) & 7;
    int c4   = (e >> 9) & 3;
    int k    = e >> 11;
    int mrow = lane & 15, quad = lane >> 4;
    int o  = (m * 16 + mrow) >> 1;
    int oc = mrow & 1;
    unsigned int hw[4];
#pragma unroll
    for (int jp = 0; jp < 4; ++jp) {
        float v[2];
#pragma unroll
        for (int jj = 0; jj < 2; ++jj) {
            int r    = quad * 8 + jp * 2 + jj;
            int i    = c4 * 16 + (r >> 1);
            int comp = r & 1;
            const float* wp = w + ((i * 64 + o) * 32 + k) * 2;
            float re = wp[0], im = wp[1];
            v[jj] = oc ? (comp ? re : im) : (comp ? -im : re);
        }
        hw[jp] = packh2(v[0], v[1]);
    }
    W2h[g] = make_uint4(hw[0], hw[1], hw[2], hw[3]);
}

// BR=0: width branch (DFT axis contiguous), writes out.
// BR=1: height branch (DFT axis strided by 128), accumulates into out.
template<int BR>
__global__ __launch_bounds__(1024, 4) void spectral(const float* __restrict__ x,
                                                    const uint4* __restrict__ w2,
                                                    float* __restrict__ out)
{
    __shared__ uint4 Ubuf[69632 / 16];            // Xs 256 cols x 136 halves; Zs overlay
    __shared__ unsigned short Ys[32 * YS_PK];     // 41472 B  -> total 111104 B

    unsigned short* Xs = (unsigned short*)Ubuf;
    unsigned int*   Zs = (unsigned int*)Ubuf;

    const int tid  = threadIdx.x;
    const int wv   = tid >> 6;        // 0..15
    const int lane = tid & 63;
    const int mrow = tid & 15;
    const int quad = (tid >> 4) & 3;
    const int bx   = blockIdx.x;
    const int b    = bx >> 3;
    const int tile = bx & 7;

    const long xb = (long)b * 1048576 + (BR == 0 ? tile * 2048 : tile * 16);
    const long ob = xb;

    // ---- stage-1 A fragments: F[kp][d], kp-tile fixed per wave ----
    const int kptile = wv & 3;
    const int igrp   = wv >> 2;
    half8 Ff[4];
#pragma unroll
    for (int s = 0; s < 4; ++s)
#pragma unroll
        for (int j = 0; j < 8; ++j) {
            int d  = s * 32 + quad * 8 + j;
            int kp = kptile * 16 + mrow;
            int k  = kp >> 1;
            float ang = TWO_PI_OVER_128 * (float)((k * d) & 127);
            float v = (kp & 1) ? -sinf(ang) : cosf(ang);
            Ff[s][j] = (_Float16)v;
        }

    // ---- mix accumulators: wave wv owns k = {2wv, 2wv+1}; Z2[o' 0..127][t 0..15] ----
    floatx4 acc[2][8];
#pragma unroll
    for (int kk = 0; kk < 2; ++kk)
#pragma unroll
        for (int m = 0; m < 8; ++m)
            acc[kk][m] = (floatx4){0.f, 0.f, 0.f, 0.f};

    // ---- prologue: stage chunk 0 (16 channels) into Xs, two groups of 4 ----
#pragma unroll
    for (int g = 0; g < 2; ++g) {
        float4 v[4];
#pragma unroll
        for (int pp = 0; pp < 4; ++pp) {
            int p = g * 4 + pp;
            if (BR == 0) {
                int idx = p * 1024 + tid;
                int col = idx >> 5, dg = idx & 31;
                v[pp] = *(const float4*)(x + xb + (long)(col >> 4) * 16384 + (col & 15) * 128 + dg * 4);
            } else {
                int i = (tid >> 9) + p * 2;
                int d = (tid >> 2) & 127, tq = (tid & 3) * 4;
                v[pp] = *(const float4*)(x + xb + (long)i * 16384 + d * 128 + tq);
            }
        }
#pragma unroll
        for (int pp = 0; pp < 4; ++pp) {
            int p = g * 4 + pp;
            if (BR == 0) {
                int idx = p * 1024 + tid;
                int col = idx >> 5, dg = idx & 31;
                *(uint2*)&Xs[col * 136 + dg * 4] =
                    make_uint2(packh2(v[pp].x, v[pp].y), packh2(v[pp].z, v[pp].w));
            } else {
                int i = (tid >> 9) + p * 2;
                int d = (tid >> 2) & 127, tq = (tid & 3) * 4;
                int colb = i * 16 + tq;
                Xs[(colb + 0) * 136 + d] = __builtin_bit_cast(unsigned short, (_Float16)v[pp].x);
                Xs[(colb + 1) * 136 + d] = __builtin_bit_cast(unsigned short, (_Float16)v[pp].y);
                Xs[(colb + 2) * 136 + d] = __builtin_bit_cast(unsigned short, (_Float16)v[pp].z);
                Xs[(colb + 3) * 136 + d] = __builtin_bit_cast(unsigned short, (_Float16)v[pp].w);
            }
        }
    }
    __syncthreads();

    // ================= chunk loop: 4 chunks x 16 input channels =================
    for (int c = 0; c < 4; ++c) {
        // ---------- issue group A (i 0..7) of next chunk ----------
        float4 pfA[4];
        if (c < 3) {
#pragma unroll
            for (int p = 0; p < 4; ++p) {
                if (BR == 0) {
                    int idx = p * 1024 + tid;
                    int col = idx >> 5, dg = idx & 31;
                    pfA[p] = *(const float4*)(x + xb + (long)((c + 1) * 16 + (col >> 4)) * 16384 + (col & 15) * 128 + dg * 4);
                } else {
                    int i = (tid >> 9) + p * 2;
                    int d = (tid >> 2) & 127, tq = (tid & 3) * 4;
                    pfA[p] = *(const float4*)(x + xb + (long)((c + 1) * 16 + i) * 16384 + d * 128 + tq);
                }
            }
        }

        // ---------- stage 1: Y = F x X -> Ys[k][t][r=2i+comp], wave does 4 i ----------
#pragma unroll
        for (int cc = 0; cc < 4; ++cc) {
            int i = igrp * 4 + cc;
            floatx4 y4 = {0.f, 0.f, 0.f, 0.f};
#pragma unroll
            for (int s = 0; s < 4; ++s) {
                uint4 bv = *(const uint4*)&Xs[(i * 16 + mrow) * 136 + s * 32 + quad * 8];
                y4 = __builtin_amdgcn_mfma_f32_16x16x32_f16(Ff[s], ash8(bv), y4, 0, 0, 0);
            }
            int k0 = kptile * 8 + quad * 2;
            unsigned int* yw = (unsigned int*)Ys;
            yw[(k0    ) * (YS_PK / 2) + mrow * (YS_PR / 2) + i] = packh2(y4[0], y4[1]);
            yw[(k0 + 1) * (YS_PK / 2) + mrow * (YS_PR / 2) + i] = packh2(y4[2], y4[3]);
        }
        __syncthreads();   // B1: Ys ready; Xs reads done

        // ---------- write group A into Xs; issue group B (i 8..15) ----------
        float4 pfB[4];
        if (c < 3) {
#pragma unroll
            for (int p = 0; p < 4; ++p) {
                if (BR == 0) {
                    int idx = p * 1024 + tid;
                    int col = idx >> 5, dg = idx & 31;
                    *(uint2*)&Xs[col * 136 + dg * 4] =
                        make_uint2(packh2(pfA[p].x, pfA[p].y), packh2(pfA[p].z, pfA[p].w));
                } else {
                    int i = (tid >> 9) + p * 2;
                    int d = (tid >> 2) & 127, tq = (tid & 3) * 4;
                    int colb = i * 16 + tq;
                    Xs[(colb + 0) * 136 + d] = __builtin_bit_cast(unsigned short, (_Float16)pfA[p].x);
                    Xs[(colb + 1) * 136 + d] = __builtin_bit_cast(unsigned short, (_Float16)pfA[p].y);
                    Xs[(colb + 2) * 136 + d] = __builtin_bit_cast(unsigned short, (_Float16)pfA[p].z);
                    Xs[(colb + 3) * 136 + d] = __builtin_bit_cast(unsigned short, (_Float16)pfA[p].w);
                }
            }
#pragma unroll
            for (int p = 0; p < 4; ++p) {
                if (BR == 0) {
                    int idx = (p + 4) * 1024 + tid;
                    int col = idx >> 5, dg = idx & 31;
                    pfB[p] = *(const float4*)(x + xb + (long)((c + 1) * 16 + (col >> 4)) * 16384 + (col & 15) * 128 + dg * 4);
                } else {
                    int i = (tid >> 9) + (p + 4) * 2;
                    int d = (tid >> 2) & 127, tq = (tid & 3) * 4;
                    pfB[p] = *(const float4*)(x + xb + (long)((c + 1) * 16 + i) * 16384 + d * 128 + tq);
                }
            }
        }

        // ---------- mix: per k one K=32 MFMA per m-tile (r spans 16 i x re/im) ----------
        {
            half8 bf0 = ash8(*(const uint4*)&Ys[(2 * wv    ) * YS_PK + mrow * YS_PR + quad * 8]);
            half8 bf1 = ash8(*(const uint4*)&Ys[(2 * wv + 1) * YS_PK + mrow * YS_PR + quad * 8]);
            // entry((k,c,m)) = ((k*4 + c)*8 + m)*64 + lane ; k+1 -> +2048
            const uint4* wp = w2 + (((2 * wv) * 4 + c) * 8) * 64 + lane;
#pragma unroll
            for (int m = 0; m < 8; ++m) {
                acc[0][m] = MFMA_K32(ash8(wp[m * 64       ]), bf0, acc[0][m]);
                acc[1][m] = MFMA_K32(ash8(wp[m * 64 + 2048]), bf1, acc[1][m]);
            }
        }

        // ---------- write group B into Xs ----------
        if (c < 3) {
#pragma unroll
            for (int p = 0; p < 4; ++p) {
                if (BR == 0) {
                    int idx = (p + 4) * 1024 + tid;
                    int col = idx >> 5, dg = idx & 31;
                    *(uint2*)&Xs[col * 136 + dg * 4] =
                        make_uint2(packh2(pfB[p].x, pfB[p].y), packh2(pfB[p].z, pfB[p].w));
                } else {
                    int i = (tid >> 9) + (p + 4) * 2;
                    int d = (tid >> 2) & 127, tq = (tid & 3) * 4;
                    int colb = i * 16 + tq;
                    Xs[(colb + 0) * 136 + d] = __builtin_bit_cast(unsigned short, (_Float16)pfB[p].x);
                    Xs[(colb + 1) * 136 + d] = __builtin_bit_cast(unsigned short, (_Float16)pfB[p].y);
                    Xs[(colb + 2) * 136 + d] = __builtin_bit_cast(unsigned short, (_Float16)pfB[p].z);
                    Xs[(colb + 3) * 136 + d] = __builtin_bit_cast(unsigned short, (_Float16)pfB[p].w);
                }
            }
        }
        __syncthreads();   // B2: Xs(c+1) ready; Ys(c) reads done
    }

    // ================= stage 3: out = G x Z, quarter of o at a time =================
    const int dt  = wv & 7;
    const int ctb = (wv >> 3) * 8;
    const int dp  = dt * 16 + mrow;
    half8 Gf[2];
#pragma unroll
    for (int s = 0; s < 2; ++s)
#pragma unroll
        for (int j = 0; j < 8; ++j) {
            int kp = s * 32 + quad * 8 + j;
            int k  = kp >> 1;
            float ang = TWO_PI_OVER_128 * (float)((k * dp) & 127);
            float v;
            if (kp == 0)      v = 1.f / 128.f;
            else if (kp == 1) v = 0.f;                       // irfft drops DC imag
            else v = (kp & 1) ? -(2.f / 128.f) * sinf(ang) : (2.f / 128.f) * cosf(ang);
            Gf[s][j] = (_Float16)v;
        }

    for (int q = 0; q < 4; ++q) {
        __syncthreads();   // prev quarter's Zs reads (or chunk-3 traffic) done
        // slot = k ^ 8*quad; reader XORs the same value, so it cancels
#pragma unroll
        for (int mm = 0; mm < 2; ++mm) {
            const int m = q * 2 + mm;
#pragma unroll
            for (int kk = 0; kk < 2; ++kk) {
                const int slot = (wv * 2 + kk) ^ (quad * 8);
                const int col  = (mm * 8 + quad * 2) * 16 + mrow;
                Zs[ col       * 36 + slot] = packh2(acc[kk][m][0], acc[kk][m][1]);
                Zs[(col + 16) * 36 + slot] = packh2(acc[kk][m][2], acc[kk][m][3]);
            }
        }
        __syncthreads();   // Zs ready

#pragma unroll
        for (int cc = 0; cc < 8; ++cc) {
            const int ct  = ctb + cc;
            const int col = ct * 16 + mrow;
            const int swz = (ct & 6) << 2;
            floatx4 o4 = {0.f, 0.f, 0.f, 0.f};
#pragma unroll
            for (int s = 0; s < 2; ++s) {
                uint4 zv = *(const uint4*)&Zs[col * 36 + ((s * 16 + quad * 4) ^ swz)];
                o4 = __builtin_amdgcn_mfma_f32_16x16x32_f16(Gf[s], ash8(zv), o4, 0, 0, 0);
            }
            const int oo = q * 16 + ct;
            const int t  = mrow;
            const int db = dt * 16 + quad * 4;
            if (BR == 0) {
                __builtin_nontemporal_store(o4, (floatx4*)(out + ob + (long)oo * 16384 + t * 128 + db));
            } else {
                float* p = out + ob + (long)oo * 16384 + (long)db * 128 + t;
                unsafeAtomicAdd(p,       o4[0]);
                unsafeAtomicAdd(p + 128, o4[1]);
                unsafeAtomicAdd(p + 256, o4[2]);
                unsafeAtomicAdd(p + 384, o4[3]);
            }
        }
    }
}

extern "C" void kernel_launch(void* const* d_in, const int* in_sizes, int n_in,
                              void* d_out, int out_size, void* d_ws, size_t ws_size,
                              hipStream_t stream) {
    const float* x  = (const float*)d_in[0];
    const float* w0 = (const float*)d_in[1];
    const float* w1 = (const float*)d_in[2];
    float* out = (float*)d_out;

    uint4* W2h = (uint4*)d_ws;                 // 2 x 65536 uint4 = 2 MB

    w2expand<<<dim3(512), dim3(256), 0, stream>>>(w0, w1, W2h);

    dim3 grid(256);    // 32 batches x 8 line-tiles
    dim3 block(1024);

    spectral<0><<<grid, block, 0, stream>>>(x, W2h,         out);  // width: writes out
    spectral<1><<<grid, block, 0, stream>>>(x, W2h + 65536, out);  // height: accumulates
}

// Round 9
// 502.040 us; speedup vs baseline: 1.1512x; 1.0024x over previous
//
#include <hip/hip_runtime.h>

// FactorizedSpectralConv2d, round 9: collapse the epilogue 8 phases -> 2.
// Full Z (64 o x 16 t x 32 k complex = 147456 B) fits LDS when overlaying Xs+Ys
// after the last chunk. Epilogue: write ALL Zs, ONE barrier, stage3 all 32 tiles
// per wave with stores drained only at kernel end (no more per-quarter
// vmcnt(0)-at-barrier store serialization).
// Main loop identical to round 8 (4 chunks x 16 ch, K=32 mix, 2 barriers/chunk).
// Kept: W2h pre-expansion, A/B split reg prefetch, BR0 nontemporal, BR1 atomics.

typedef _Float16 half8  __attribute__((ext_vector_type(8)));
typedef _Float16 half2v __attribute__((ext_vector_type(2)));
typedef float    floatx4 __attribute__((ext_vector_type(4)));

#define TWO_PI_OVER_128 0.049087385212340517f

__device__ __forceinline__ unsigned int packh2(float a, float b) {
    half2v h; h[0] = (_Float16)a; h[1] = (_Float16)b;
    return __builtin_bit_cast(unsigned int, h);
}
__device__ __forceinline__ half8 ash8(uint4 u) { return __builtin_bit_cast(half8, u); }

#define MFMA_K32(A,B,C) __builtin_amdgcn_mfma_f32_16x16x32_f16((A),(B),(C),0,0,0)

#define YS_PR 40    // halves per t row (32 r + 8 pad)
#define YS_PK 648   // halves per k slice (16*40 + 8)

// ---- pre-kernel: expand weights into half8 A-fragments for the K=32 mix ----
// entry (per branch) = ((k*4 + c4)*8 + m)*64 + lane ; uint4 = 8 halves j=0..7:
//   k-slot r = quad*8 + j ; i = c4*16 + (r>>1) ; comp = r&1
//   o' = m*16 + mrow ; o = o'>>1 ; oc = o'&1
//   oc==0 (re row): comp0 -> re, comp1 -> -im ; oc==1 (im row): comp0 -> im, comp1 -> re
__global__ __launch_bounds__(256) void w2expand(const float* __restrict__ w0,
                                                const float* __restrict__ w1,
                                                uint4* __restrict__ W2h)
{
    int g = blockIdx.x * 256 + threadIdx.x;       // 2 * 65536 entries
    const float* w = (g >> 16) ? w1 : w0;
    int e    = g & 65535;
    int lane = e & 63;
    int m    = (e >> 6) & 7;
    int c4   = (e >> 9) & 3;
    int k    = e >> 11;
    int mrow = lane & 15, quad = lane >> 4;
    int o  = (m * 16 + mrow) >> 1;
    int oc = mrow & 1;
    unsigned int hw[4];
#pragma unroll
    for (int jp = 0; jp < 4; ++jp) {
        float v[2];
#pragma unroll
        for (int jj = 0; jj < 2; ++jj) {
            int r    = quad * 8 + jp * 2 + jj;
            int i    = c4 * 16 + (r >> 1);
            int comp = r & 1;
            const float* wp = w + ((i * 64 + o) * 32 + k) * 2;
            float re = wp[0], im = wp[1];
            v[jj] = oc ? (comp ? re : im) : (comp ? -im : re);
        }
        hw[jp] = packh2(v[0], v[1]);
    }
    W2h[g] = make_uint4(hw[0], hw[1], hw[2], hw[3]);
}

// BR=0: width branch (DFT axis contiguous), writes out.
// BR=1: height branch (DFT axis strided by 128), accumulates into out.
template<int BR>
__global__ __launch_bounds__(1024, 4) void spectral(const float* __restrict__ x,
                                                    const uint4* __restrict__ w2,
                                                    float* __restrict__ out)
{
    // One region, three overlays:
    //   main loop: Xs = bytes [0, 69632) ; Ys = bytes [69632, 111104)
    //   epilogue:  Zs = bytes [0, 147456)   (1024 cols x 36 uints)
    __shared__ uint4 SMEM[147456 / 16];

    unsigned short* Xs = (unsigned short*)SMEM;
    unsigned short* Ys = (unsigned short*)SMEM + 69632 / 2;
    unsigned int*   Zs = (unsigned int*)SMEM;

    const int tid  = threadIdx.x;
    const int wv   = tid >> 6;        // 0..15
    const int lane = tid & 63;
    const int mrow = tid & 15;
    const int quad = (tid >> 4) & 3;
    const int bx   = blockIdx.x;
    const int b    = bx >> 3;
    const int tile = bx & 7;

    const long xb = (long)b * 1048576 + (BR == 0 ? tile * 2048 : tile * 16);
    const long ob = xb;

    // ---- stage-1 A fragments: F[kp][d], kp-tile fixed per wave ----
    const int kptile = wv & 3;
    const int igrp   = wv >> 2;
    half8 Ff[4];
#pragma unroll
    for (int s = 0; s < 4; ++s)
#pragma unroll
        for (int j = 0; j < 8; ++j) {
            int d  = s * 32 + quad * 8 + j;
            int kp = kptile * 16 + mrow;
            int k  = kp >> 1;
            float ang = TWO_PI_OVER_128 * (float)((k * d) & 127);
            float v = (kp & 1) ? -sinf(ang) : cosf(ang);
            Ff[s][j] = (_Float16)v;
        }

    // ---- mix accumulators: wave wv owns k = {2wv, 2wv+1}; Z2[o' 0..127][t 0..15] ----
    floatx4 acc[2][8];
#pragma unroll
    for (int kk = 0; kk < 2; ++kk)
#pragma unroll
        for (int m = 0; m < 8; ++m)
            acc[kk][m] = (floatx4){0.f, 0.f, 0.f, 0.f};

    // ---- prologue: stage chunk 0 (16 channels) into Xs, two groups of 4 ----
#pragma unroll
    for (int g = 0; g < 2; ++g) {
        float4 v[4];
#pragma unroll
        for (int pp = 0; pp < 4; ++pp) {
            int p = g * 4 + pp;
            if (BR == 0) {
                int idx = p * 1024 + tid;
                int col = idx >> 5, dg = idx & 31;
                v[pp] = *(const float4*)(x + xb + (long)(col >> 4) * 16384 + (col & 15) * 128 + dg * 4);
            } else {
                int i = (tid >> 9) + p * 2;
                int d = (tid >> 2) & 127, tq = (tid & 3) * 4;
                v[pp] = *(const float4*)(x + xb + (long)i * 16384 + d * 128 + tq);
            }
        }
#pragma unroll
        for (int pp = 0; pp < 4; ++pp) {
            int p = g * 4 + pp;
            if (BR == 0) {
                int idx = p * 1024 + tid;
                int col = idx >> 5, dg = idx & 31;
                *(uint2*)&Xs[col * 136 + dg * 4] =
                    make_uint2(packh2(v[pp].x, v[pp].y), packh2(v[pp].z, v[pp].w));
            } else {
                int i = (tid >> 9) + p * 2;
                int d = (tid >> 2) & 127, tq = (tid & 3) * 4;
                int colb = i * 16 + tq;
                Xs[(colb + 0) * 136 + d] = __builtin_bit_cast(unsigned short, (_Float16)v[pp].x);
                Xs[(colb + 1) * 136 + d] = __builtin_bit_cast(unsigned short, (_Float16)v[pp].y);
                Xs[(colb + 2) * 136 + d] = __builtin_bit_cast(unsigned short, (_Float16)v[pp].z);
                Xs[(colb + 3) * 136 + d] = __builtin_bit_cast(unsigned short, (_Float16)v[pp].w);
            }
        }
    }
    __syncthreads();

    // ================= chunk loop: 4 chunks x 16 input channels =================
    for (int c = 0; c < 4; ++c) {
        // ---------- issue group A (i 0..7) of next chunk ----------
        float4 pfA[4];
        if (c < 3) {
#pragma unroll
            for (int p = 0; p < 4; ++p) {
                if (BR == 0) {
                    int idx = p * 1024 + tid;
                    int col = idx >> 5, dg = idx & 31;
                    pfA[p] = *(const float4*)(x + xb + (long)((c + 1) * 16 + (col >> 4)) * 16384 + (col & 15) * 128 + dg * 4);
                } else {
                    int i = (tid >> 9) + p * 2;
                    int d = (tid >> 2) & 127, tq = (tid & 3) * 4;
                    pfA[p] = *(const float4*)(x + xb + (long)((c + 1) * 16 + i) * 16384 + d * 128 + tq);
                }
            }
        }

        // ---------- stage 1: Y = F x X -> Ys[k][t][r=2i+comp], wave does 4 i ----------
#pragma unroll
        for (int cc = 0; cc < 4; ++cc) {
            int i = igrp * 4 + cc;
            floatx4 y4 = {0.f, 0.f, 0.f, 0.f};
#pragma unroll
            for (int s = 0; s < 4; ++s) {
                uint4 bv = *(const uint4*)&Xs[(i * 16 + mrow) * 136 + s * 32 + quad * 8];
                y4 = __builtin_amdgcn_mfma_f32_16x16x32_f16(Ff[s], ash8(bv), y4, 0, 0, 0);
            }
            int k0 = kptile * 8 + quad * 2;
            unsigned int* yw = (unsigned int*)Ys;
            yw[(k0    ) * (YS_PK / 2) + mrow * (YS_PR / 2) + i] = packh2(y4[0], y4[1]);
            yw[(k0 + 1) * (YS_PK / 2) + mrow * (YS_PR / 2) + i] = packh2(y4[2], y4[3]);
        }
        __syncthreads();   // B1: Ys ready; Xs reads done

        // ---------- write group A into Xs; issue group B (i 8..15) ----------
        float4 pfB[4];
        if (c < 3) {
#pragma unroll
            for (int p = 0; p < 4; ++p) {
                if (BR == 0) {
                    int idx = p * 1024 + tid;
                    int col = idx >> 5, dg = idx & 31;
                    *(uint2*)&Xs[col * 136 + dg * 4] =
                        make_uint2(packh2(pfA[p].x, pfA[p].y), packh2(pfA[p].z, pfA[p].w));
                } else {
                    int i = (tid >> 9) + p * 2;
                    int d = (tid >> 2) & 127, tq = (tid & 3) * 4;
                    int colb = i * 16 + tq;
                    Xs[(colb + 0) * 136 + d] = __builtin_bit_cast(unsigned short, (_Float16)pfA[p].x);
                    Xs[(colb + 1) * 136 + d] = __builtin_bit_cast(unsigned short, (_Float16)pfA[p].y);
                    Xs[(colb + 2) * 136 + d] = __builtin_bit_cast(unsigned short, (_Float16)pfA[p].z);
                    Xs[(colb + 3) * 136 + d] = __builtin_bit_cast(unsigned short, (_Float16)pfA[p].w);
                }
            }
#pragma unroll
            for (int p = 0; p < 4; ++p) {
                if (BR == 0) {
                    int idx = (p + 4) * 1024 + tid;
                    int col = idx >> 5, dg = idx & 31;
                    pfB[p] = *(const float4*)(x + xb + (long)((c + 1) * 16 + (col >> 4)) * 16384 + (col & 15) * 128 + dg * 4);
                } else {
                    int i = (tid >> 9) + (p + 4) * 2;
                    int d = (tid >> 2) & 127, tq = (tid & 3) * 4;
                    pfB[p] = *(const float4*)(x + xb + (long)((c + 1) * 16 + i) * 16384 + d * 128 + tq);
                }
            }
        }

        // ---------- mix: per k one K=32 MFMA per m-tile (r spans 16 i x re/im) ----------
        {
            half8 bf0 = ash8(*(const uint4*)&Ys[(2 * wv    ) * YS_PK + mrow * YS_PR + quad * 8]);
            half8 bf1 = ash8(*(const uint4*)&Ys[(2 * wv + 1) * YS_PK + mrow * YS_PR + quad * 8]);
            // entry((k,c,m)) = ((k*4 + c)*8 + m)*64 + lane ; k+1 -> +2048
            const uint4* wp = w2 + (((2 * wv) * 4 + c) * 8) * 64 + lane;
#pragma unroll
            for (int m = 0; m < 8; ++m) {
                acc[0][m] = MFMA_K32(ash8(wp[m * 64       ]), bf0, acc[0][m]);
                acc[1][m] = MFMA_K32(ash8(wp[m * 64 + 2048]), bf1, acc[1][m]);
            }
        }

        // ---------- write group B into Xs ----------
        if (c < 3) {
#pragma unroll
            for (int p = 0; p < 4; ++p) {
                if (BR == 0) {
                    int idx = (p + 4) * 1024 + tid;
                    int col = idx >> 5, dg = idx & 31;
                    *(uint2*)&Xs[col * 136 + dg * 4] =
                        make_uint2(packh2(pfB[p].x, pfB[p].y), packh2(pfB[p].z, pfB[p].w));
                } else {
                    int i = (tid >> 9) + (p + 4) * 2;
                    int d = (tid >> 2) & 127, tq = (tid & 3) * 4;
                    int colb = i * 16 + tq;
                    Xs[(colb + 0) * 136 + d] = __builtin_bit_cast(unsigned short, (_Float16)pfB[p].x);
                    Xs[(colb + 1) * 136 + d] = __builtin_bit_cast(unsigned short, (_Float16)pfB[p].y);
                    Xs[(colb + 2) * 136 + d] = __builtin_bit_cast(unsigned short, (_Float16)pfB[p].z);
                    Xs[(colb + 3) * 136 + d] = __builtin_bit_cast(unsigned short, (_Float16)pfB[p].w);
                }
            }
        }
        __syncthreads();   // B2: Xs(c+1) ready; Ys(c) reads done
    }

    // ================= stage 3: single-phase epilogue =================
    // After the final B2, Xs/Ys are dead -> overlay full Zs[col = o*16+t][36 uints].
    // writer: o = m*8 + quad*2 + p, slot = k ^ (quad*8); since bits1:2 of o ARE the
    // writer quad, reader swz = (o&6)<<2 equals writer quad*8 -> XOR cancels.
    const int dt   = wv & 7;          // d-block 0..7
    const int half = wv >> 3;         // o-half 0..1
    const int dp   = dt * 16 + mrow;
    half8 Gf[2];
#pragma unroll
    for (int s = 0; s < 2; ++s)
#pragma unroll
        for (int j = 0; j < 8; ++j) {
            int kp = s * 32 + quad * 8 + j;
            int k  = kp >> 1;
            float ang = TWO_PI_OVER_128 * (float)((k * dp) & 127);
            float v;
            if (kp == 0)      v = 1.f / 128.f;
            else if (kp == 1) v = 0.f;                       // irfft drops DC imag
            else v = (kp & 1) ? -(2.f / 128.f) * sinf(ang) : (2.f / 128.f) * cosf(ang);
            Gf[s][j] = (_Float16)v;
        }

    // ---- one phase: ALL Zs writes ----
#pragma unroll
    for (int m = 0; m < 8; ++m)
#pragma unroll
        for (int kk = 0; kk < 2; ++kk) {
            const int slot = (wv * 2 + kk) ^ (quad * 8);
            const int col  = (m * 8 + quad * 2) * 16 + mrow;
            Zs[ col       * 36 + slot] = packh2(acc[kk][m][0], acc[kk][m][1]);
            Zs[(col + 16) * 36 + slot] = packh2(acc[kk][m][2], acc[kk][m][3]);
        }
    __syncthreads();   // Zs ready — the ONLY epilogue barrier

    // ---- one phase: all 32 output tiles per wave, stores drain at endpgm ----
#pragma unroll
    for (int cc = 0; cc < 32; ++cc) {
        const int oo  = half * 32 + cc;
        const int col = oo * 16 + mrow;
        const int swz = (oo & 6) << 2;
        floatx4 o4 = {0.f, 0.f, 0.f, 0.f};
#pragma unroll
        for (int s = 0; s < 2; ++s) {
            uint4 zv = *(const uint4*)&Zs[col * 36 + ((s * 16 + quad * 4) ^ swz)];
            o4 = __builtin_amdgcn_mfma_f32_16x16x32_f16(Gf[s], ash8(zv), o4, 0, 0, 0);
        }
        const int t  = mrow;
        const int db = dt * 16 + quad * 4;
        if (BR == 0) {
            __builtin_nontemporal_store(o4, (floatx4*)(out + ob + (long)oo * 16384 + t * 128 + db));
        } else {
            float* p = out + ob + (long)oo * 16384 + (long)db * 128 + t;
            unsafeAtomicAdd(p,       o4[0]);
            unsafeAtomicAdd(p + 128, o4[1]);
            unsafeAtomicAdd(p + 256, o4[2]);
            unsafeAtomicAdd(p + 384, o4[3]);
        }
    }
}

extern "C" void kernel_launch(void* const* d_in, const int* in_sizes, int n_in,
                              void* d_out, int out_size, void* d_ws, size_t ws_size,
                              hipStream_t stream) {
    const float* x  = (const float*)d_in[0];
    const float* w0 = (const float*)d_in[1];
    const float* w1 = (const float*)d_in[2];
    float* out = (float*)d_out;

    uint4* W2h = (uint4*)d_ws;                 // 2 x 65536 uint4 = 2 MB

    w2expand<<<dim3(512), dim3(256), 0, stream>>>(w0, w1, W2h);

    dim3 grid(256);    // 32 batches x 8 line-tiles
    dim3 block(1024);

    spectral<0><<<grid, block, 0, stream>>>(x, W2h,         out);  // width: writes out
    spectral<1><<<grid, block, 0, stream>>>(x, W2h + 65536, out);  // height: accumulates
}